// Round 3
// baseline (250.302 us; speedup 1.0000x reference)
//
#include <hip/hip_runtime.h>
#include <hip/hip_bf16.h>

#define HW 128
#define GNUM 2
#define BATCH 4
#define W2T_FLOATS 331776                      // 663552 shorts = 1.33 MB
#define OBT_STRIDE (GNUM * 18 * 2 * 512)       // shorts per hi/lo sub-buffer
#define OBT_FLOATS 36864                       // 73728 shorts (hi+lo)

typedef short s16x8 __attribute__((ext_vector_type(8)));
typedef float f32x4 __attribute__((ext_vector_type(4)));

__device__ inline unsigned short f2bf(float f) {
    union { float f; unsigned u; } v;
    v.f = f;
    unsigned r = (v.u + 0x7fffu + ((v.u >> 16) & 1u)) >> 16;
    return (unsigned short)r;
}
__device__ inline unsigned pk2bf(float lo, float hi) {   // v_cvt_pk_bf16_f32
    __hip_bfloat162 r = __float22bfloat162_rn(float2{lo, hi});
    return *(unsigned*)&r;
}
__device__ inline float blo(unsigned u) {
    union { unsigned u; float f; } v; v.u = u << 16; return v.f;
}
__device__ inline float bhi(unsigned u) {
    union { unsigned u; float f; } v; v.u = u & 0xffff0000u; return v.f;
}

// ---------------------------------------------------------------------------
// prep_kernel:
//   bx 0..8  -> W2[g,j,tap2][k,f] = bf16(pw_w[k,f]*dw_w[tap2,k]) B-frags
//               (same frag layout as the validated pwt, + tap2 axis) and
//               bias2 partial Σ pw*dw_b (validated).
//   bx 9..26 -> off_w -> bf16 hi/lo B-frags (validated R5-R7, unchanged).
// ---------------------------------------------------------------------------
__global__ __launch_bounds__(256) void prep_kernel(
    const float* __restrict__ pw_w, const float* __restrict__ dw_b,
    const float* __restrict__ off_w, const float* __restrict__ dw_w,
    unsigned short* __restrict__ w2t, unsigned short* __restrict__ obt,
    float* __restrict__ bias2) {
    const int g = blockIdx.y;
    const int t = threadIdx.x;
    if (blockIdx.x < 9) {
        const int j = blockIdx.x;
        const int wv = t >> 6, lane = t & 63;
        const int f = wv * 16 + (lane & 15);
        const int kbase = (lane >> 4) << 3;
        float vv[2][8];
        float part = 0.f;
#pragma unroll
        for (int ks = 0; ks < 2; ++ks)
#pragma unroll
            for (int i = 0; i < 8; ++i) {
                int kin = j * 64 + ks * 32 + kbase + i;
                float v = pw_w[(g * 576 + kin) * 64 + f];
                vv[ks][i] = v;
                part += v * dw_b[g * 576 + kin];
            }
        atomicAdd(&bias2[g * 64 + f], part);
        for (int tap2 = 0; tap2 < 9; ++tap2) {
#pragma unroll
            for (int ks = 0; ks < 2; ++ks) {
                s16x8 w;
#pragma unroll
                for (int i = 0; i < 8; ++i) {
                    int kin = j * 64 + ks * 32 + kbase + i;
                    w[i] = (short)f2bf(vv[ks][i] *
                                       dw_w[(g * 9 + tap2) * 576 + kin]);
                }
                *(s16x8*)&w2t[(((((g * 9 + j) * 9 + tap2) * 4 + wv) * 2 + ks)
                               << 9) + lane * 8] = w;
            }
        }
    } else {
        const int s = blockIdx.x - 9;
        const int tap = s >> 1;
        for (int e = t; e < 1024; e += 256) {
            int nt = e >> 9, le = e & 511;
            int lane = le >> 3, i = le & 7;
            int k = ((lane >> 4) << 3) + i;
            int c = ((s & 1) << 5) + k;
            int n = (nt << 4) + (lane & 15);
            float v = (n < 18) ? off_w[((g * 9 + tap) * 64 + c) * 18 + n] : 0.f;
            unsigned short hi = f2bf(v);
            unsigned short lo = f2bf(v - blo(hi));
            int idx = (((g * 18 + s) * 2 + nt) << 9) + le;
            obt[idx] = hi;
            obt[OBT_STRIDE + idx] = lo;
        }
    }
}

// ---------------------------------------------------------------------------
// deform_fused: ONE kernel per 8x8 output tile of (b,g):
//   Stage 0: offset conv (3x3 SAME, 64->18, split-precision bf16 MFMA) for
//            the 10x10 halo positions, from a 12x12 x-halo -> offs[] in LDS.
//   Stage 1 (R2 fold): per tap j: W (bilinear wts) -> S (float4 gather) ->
//            B' (depthwise FOLDED into pointwise: 9 shifted MFMAs over samp
//            with W2 = dw*pw B-frags).  Phase A + dwa deleted; 2 barriers/tap.
// LDS (31,136 B -> up to 5 blocks/CU):
//   [0,20736):  xh ushort[144*72] (stage 0)  ALIASED WITH samp ushort[100*72]
//   [20736..):  offs float[100*18]  (7.2 KB)
//   [27936..):  wlw float4[100] ; wli int4[100]  (3.2 KB)
// ---------------------------------------------------------------------------
__global__ __launch_bounds__(256, 4) void deform_fused(
    const float* __restrict__ x, const unsigned short* __restrict__ obt,
    const float* __restrict__ off_b, const unsigned short* __restrict__ w2t,
    const float* __restrict__ bias2, const float* __restrict__ pw_b,
    float* __restrict__ out) {
    __shared__ char smem[31136];
    unsigned short* xh = (unsigned short*)smem;            // stage 0 only
    unsigned short* samp = (unsigned short*)smem;          // stage 1
    float* offs = (float*)(smem + 20736);
    float4* wlw = (float4*)(smem + 27936);
    int4* wli = (int4*)(smem + 29536);

    const int b = blockIdx.x >> 1, g = blockIdx.x & 1;
    const int tileIdx = blockIdx.y;
    const int h0 = (tileIdx >> 4) << 3, w0 = (tileIdx & 15) << 3;
    const int t = threadIdx.x;
    const int lane = t & 63;
    const int wv = __builtin_amdgcn_readfirstlane(t >> 6);
    const int kq = (lane >> 4) << 3;
    const int col = lane & 15;
    const int rq = (lane >> 4) << 2;

    // ================= Stage 0: offset conv for the halo =================
    f32x4 oacc[2][2];
#pragma unroll
    for (int sl = 0; sl < 2; ++sl)
#pragma unroll
        for (int nt = 0; nt < 2; ++nt) oacc[sl][nt] = (f32x4){0.f, 0.f, 0.f, 0.f};
    int mbase[2];
#pragma unroll
    for (int sl = 0; sl < 2; ++sl) {
        int mt = wv + (sl << 2);
        int m = mt * 16 + col;
        if (mt < 7 && m < 100) {
            int opy = m / 10, opx = m - opy * 10;
            mbase[sl] = opy * 12 + opx;
        } else
            mbase[sl] = 0;
    }
    for (int q = 0; q < 2; ++q) {
        if (q) __syncthreads();
        // stage 12x12 halo x 32ch (this q-half), fp32 -> hi/lo bf16
        for (int idx = t; idx < 144 * 8; idx += 256) {
            int sp = idx >> 3, cq = idx & 7;
            int sy = sp / 12, sx = sp - sy * 12;
            int gy = h0 - 2 + sy, gx = w0 - 2 + sx;
            uint2 hp = {0, 0}, lp = {0, 0};
            if ((unsigned)gy < HW && (unsigned)gx < HW) {
                const float4 v = *(const float4*)&x[(((b * HW + gy) * HW + gx)
                                                    << 7) +
                                                   (g << 6) + (q << 5) + (cq << 2)];
                hp.x = pk2bf(v.x, v.y);
                hp.y = pk2bf(v.z, v.w);
                lp.x = pk2bf(v.x - blo(hp.x), v.y - bhi(hp.x));
                lp.y = pk2bf(v.z - blo(hp.y), v.w - bhi(hp.y));
            }
            *(uint2*)&xh[sp * 72 + (cq << 2)] = hp;
            *(uint2*)&xh[sp * 72 + 32 + (cq << 2)] = lp;
        }
        __syncthreads();
        for (int tap = 0; tap < 9; ++tap) {
            const int s = (tap << 1) + q;
            const int ky = tap / 3, kx = tap - ky * 3;
            const int shift = ky * 12 + kx;
            const int bidx = ((g * 18 + s) << 1) << 9;
            s16x8 bh0 = *(const s16x8*)&obt[bidx + lane * 8];
            s16x8 bh1 = *(const s16x8*)&obt[bidx + 512 + lane * 8];
            s16x8 bl0 = *(const s16x8*)&obt[OBT_STRIDE + bidx + lane * 8];
            s16x8 bl1 = *(const s16x8*)&obt[OBT_STRIDE + bidx + 512 + lane * 8];
#pragma unroll
            for (int sl = 0; sl < 2; ++sl) {
                if (wv + (sl << 2) < 7) {   // wave-uniform guard
                    const int base2 = (mbase[sl] + shift) * 72 + kq;
                    s16x8 ah = *(const s16x8*)&xh[base2];
                    s16x8 al = *(const s16x8*)&xh[base2 + 32];
                    oacc[sl][0] = __builtin_amdgcn_mfma_f32_16x16x32_bf16(
                        ah, bh0, oacc[sl][0], 0, 0, 0);
                    oacc[sl][1] = __builtin_amdgcn_mfma_f32_16x16x32_bf16(
                        ah, bh1, oacc[sl][1], 0, 0, 0);
                    oacc[sl][0] = __builtin_amdgcn_mfma_f32_16x16x32_bf16(
                        al, bh0, oacc[sl][0], 0, 0, 0);
                    oacc[sl][1] = __builtin_amdgcn_mfma_f32_16x16x32_bf16(
                        al, bh1, oacc[sl][1], 0, 0, 0);
                    oacc[sl][0] = __builtin_amdgcn_mfma_f32_16x16x32_bf16(
                        ah, bl0, oacc[sl][0], 0, 0, 0);
                    oacc[sl][1] = __builtin_amdgcn_mfma_f32_16x16x32_bf16(
                        ah, bl1, oacc[sl][1], 0, 0, 0);
                }
            }
        }
    }
    // write offs[m][o] = conv + off_b   (C-layout: row = rq+i, col)
#pragma unroll
    for (int sl = 0; sl < 2; ++sl) {
        int mt = wv + (sl << 2);
        if (mt < 7) {
#pragma unroll
            for (int nt = 0; nt < 2; ++nt) {
                int o = (nt << 4) + col;
                if (o < 18) {
                    float ob = off_b[g * 18 + o];
#pragma unroll
                    for (int i = 0; i < 4; ++i) {
                        int m = mt * 16 + rq + i;
                        if (m < 100) offs[m * 18 + o] = oacc[sl][nt][i] + ob;
                    }
                }
            }
        }
    }
    __syncthreads();   // offs visible; xh reads done before samp overwrites

    // ================= Stage 1: sample -> folded dw+pw MFMA ==============
    const int grp = t >> 4, sl16 = t & 15;
    // per-thread LDS base for folded A-frag reads (all 72 reads use
    // compile-time immediate offsets off this base)
    const int sbase = ((col >> 3) * 10 + (col & 7)) * 72 + kq;
    // per-thread w2t base for this (g, wv, lane); tap2/ks/j add offsets
    const unsigned short* w2b = w2t + (((g * 9) * 72 + wv * 2) << 9) + lane * 8;

    const float bs = bias2[g * 64 + (wv << 4) + col] +
                     pw_b[g * 64 + (wv << 4) + col];
    f32x4 acc[4];
#pragma unroll
    for (int mt = 0; mt < 4; ++mt) acc[mt] = (f32x4){bs, bs, bs, bs};

    for (int j = 0; j < 9; ++j) {
        const int jy = j / 3, jx = j - jy * 3;
        // ---- Phase W: bilinear weights + corner offsets, one thread per sp
        if (t < 100) {
            const int sp = t;
            const int spy = sp / 10, spx = sp - spy * 10;
            const int gy = h0 - 1 + spy, gx = w0 - 1 + spx;
            float4 w4 = {0.f, 0.f, 0.f, 0.f};
            int4 ii = {b << 21, 0, 0, 0};
            if ((unsigned)gy < HW && (unsigned)gx < HW) {
                const float ox = offs[sp * 18 + 2 * j];
                const float oy = offs[sp * 18 + 2 * j + 1];
                float xf = fminf(fmaxf((float)(gx + jx - 1) + ox, 0.f), 127.f);
                float yf = fminf(fmaxf((float)(gy + jy - 1) + oy, 0.f), 127.f);
                float x0 = floorf(xf), y0 = floorf(yf);
                float x1 = fminf(x0 + 1.f, 127.f);
                float y1 = fminf(y0 + 1.f, 127.f);
                w4.x = (x1 - xf) * (y1 - yf);
                w4.y = (x1 - xf) * (yf - y0);
                w4.z = (xf - x0) * (y1 - yf);
                w4.w = (xf - x0) * (yf - y0);
                const int x0i = (int)x0, y0i = (int)y0;
                ii.x = ((b * HW + y0i) * HW + x0i) << 7;
                ii.y = ((int)x1 - x0i) << 7;
                ii.z = ((int)y1 - y0i) << 14;
            }
            wlw[sp] = w4;
            wli[sp] = ii;
        }
        __syncthreads();
        // ---- Phase S: float4 gather; 16 lanes per sample position
        for (int it = 0; it < 7; ++it) {
            const int sp = (it << 4) + grp;
            if (sp < 100) {
                const float4 w4 = wlw[sp];
                const int4 ii = wli[sp];
                const float* xa = x + ii.x + (g << 6) + (sl16 << 2);
                const float4 va = *(const float4*)xa;
                const float4 vb = *(const float4*)(xa + ii.z);
                const float4 vc = *(const float4*)(xa + ii.y);
                const float4 vd = *(const float4*)(xa + ii.y + ii.z);
                float r0 = w4.x * va.x + w4.y * vb.x + w4.z * vc.x + w4.w * vd.x;
                float r1 = w4.x * va.y + w4.y * vb.y + w4.z * vc.y + w4.w * vd.y;
                float r2 = w4.x * va.z + w4.y * vb.z + w4.z * vc.z + w4.w * vd.z;
                float r3 = w4.x * va.w + w4.y * vb.w + w4.z * vc.w + w4.w * vd.w;
                uint2 pk;
                pk.x = pk2bf(r0, r1);
                pk.y = pk2bf(r2, r3);
                *(uint2*)&samp[sp * 72 + (sl16 << 2)] = pk;
            }
        }
        __syncthreads();
        // ---- Phase B': folded depthwise+pointwise, 9 shifted MFMAs
        const unsigned short* w2j = w2b + ((j * 72) << 9);
#pragma unroll
        for (int t2 = 0; t2 < 9; ++t2) {
            const int ky = t2 / 3, kx = t2 - ky * 3;
            s16x8 b0 = *(const s16x8*)(w2j + ((t2 * 8 + 0) << 9));
            s16x8 b1 = *(const s16x8*)(w2j + ((t2 * 8 + 1) << 9));
#pragma unroll
            for (int mt = 0; mt < 4; ++mt) {
                const unsigned short* ap =
                    &samp[sbase + (((mt << 1) + ky) * 10 + kx) * 72];
                s16x8 a0 = *(const s16x8*)ap;
                s16x8 a1 = *(const s16x8*)(ap + 32);
                acc[mt] = __builtin_amdgcn_mfma_f32_16x16x32_bf16(
                    a0, b0, acc[mt], 0, 0, 0);
                acc[mt] = __builtin_amdgcn_mfma_f32_16x16x32_bf16(
                    a1, b1, acc[mt], 0, 0, 0);
            }
        }
    }
    // ---- epilogue: C-layout col=lane&15, row=(lane>>4)*4+i
    const int fb = wv << 4;
#pragma unroll
    for (int mt = 0; mt < 4; ++mt)
#pragma unroll
        for (int i = 0; i < 4; ++i) {
            int m = mt * 16 + rq + i;
            out[((b * HW + h0 + (m >> 3)) * HW + (w0 + (m & 7))) * 128 +
                (g << 6) + fb + col] = acc[mt][i];
        }
}

extern "C" void kernel_launch(void* const* d_in, const int* in_sizes, int n_in,
                              void* d_out, int out_size, void* d_ws,
                              size_t ws_size, hipStream_t stream) {
    const float* x = (const float*)d_in[0];
    const float* off_w = (const float*)d_in[1];
    const float* off_b = (const float*)d_in[2];
    const float* dw_w = (const float*)d_in[3];
    const float* dw_b = (const float*)d_in[4];
    const float* pw_w = (const float*)d_in[5];
    const float* pw_b = (const float*)d_in[6];

    // workspace layout (floats): [w2t | obt | bias2]  (~1.48 MB)
    float* wsf = (float*)d_ws;
    unsigned short* w2t = (unsigned short*)wsf;                // 1327104 B
    unsigned short* obt = (unsigned short*)(wsf + W2T_FLOATS); // 147456 B
    float* bias2 = wsf + W2T_FLOATS + OBT_FLOATS;              // 512 B

    hipMemsetAsync(bias2, 0, GNUM * 64 * sizeof(float), stream);
    prep_kernel<<<dim3(27, GNUM), dim3(256), 0, stream>>>(pw_w, dw_b, off_w,
                                                          dw_w, w2t, obt,
                                                          bias2);
    deform_fused<<<dim3(BATCH * GNUM, 256), dim3(256), 0, stream>>>(
        x, obt, off_b, w2t, bias2, pw_b, (float*)d_out);
}

// Round 6
// 200.101 us; speedup vs baseline: 1.2509x; 1.2509x over previous
//
#include <hip/hip_runtime.h>
#include <hip/hip_bf16.h>

#define HW 128
#define GNUM 2
#define BATCH 4
#define OBT_STRIDE (GNUM * 18 * 2 * 512)       // shorts per hi/lo sub-buffer
#define PWT_FLOATS 36864                       // 73728 shorts (f16)
#define OBT_FLOATS 36864                       // 73728 shorts (hi+lo bf16)
#define DWP_WORDS 5184                         // 2g*9tap2*9j*32 u32 (f16x2)

typedef short s16x8 __attribute__((ext_vector_type(8)));
typedef _Float16 f16x8 __attribute__((ext_vector_type(8)));
typedef _Float16 f16x2 __attribute__((ext_vector_type(2)));
typedef __fp16 h16x2 __attribute__((ext_vector_type(2)));   // cvt_pkrtz ret type
typedef float f32x4 __attribute__((ext_vector_type(4)));

__device__ inline unsigned short f2bf(float f) {
    union { float f; unsigned u; } v;
    v.f = f;
    unsigned r = (v.u + 0x7fffu + ((v.u >> 16) & 1u)) >> 16;
    return (unsigned short)r;
}
__device__ inline unsigned pk2bf(float lo, float hi) {   // v_cvt_pk_bf16_f32
    __hip_bfloat162 r = __float22bfloat162_rn(float2{lo, hi});
    return *(unsigned*)&r;
}
__device__ inline float blo(unsigned u) {
    union { unsigned u; float f; } v; v.u = u << 16; return v.f;
}
__device__ inline float bhi(unsigned u) {
    union { unsigned u; float f; } v; v.u = u & 0xffff0000u; return v.f;
}
__device__ inline unsigned short f2h(float f) {
    _Float16 h = (_Float16)f;
    return *(unsigned short*)&h;
}
__device__ inline unsigned pk2h(float lo, float hi) {    // v_cvt_pkrtz_f16_f32
    union { h16x2 h; unsigned u; } v;
    v.h = __builtin_amdgcn_cvt_pkrtz(lo, hi);
    return v.u;
}
__device__ inline f16x2 u2h(unsigned u) {
    union { unsigned u; f16x2 h; } v; v.u = u; return v.h;
}
__device__ inline unsigned h2u(f16x2 h) {
    union { unsigned u; f16x2 h; } v; v.h = h; return v.u;
}

// ---------------------------------------------------------------------------
// prep_kernel:
//   bx 0..8  -> pw_w -> f16 B-frags (pwt, layout validated in R2) + bias
//               partial Σ pw*dw_b; ALSO packs dw_w into dwp[g][tap2][j][c/2]
//               as f16x2 pairs for the packed-f16 depthwise.
//   bx 9..26 -> off_w -> bf16 hi/lo B-frags (validated R5-R7, unchanged).
// ---------------------------------------------------------------------------
__global__ __launch_bounds__(256) void prep_kernel(
    const float* __restrict__ pw_w, const float* __restrict__ dw_b,
    const float* __restrict__ off_w, const float* __restrict__ dw_w,
    unsigned short* __restrict__ pwt, unsigned short* __restrict__ obt,
    unsigned* __restrict__ dwp, float* __restrict__ bias2) {
    const int g = blockIdx.y;
    const int t = threadIdx.x;
    if (blockIdx.x < 9) {
        const int j = blockIdx.x;
        const int wv = t >> 6, lane = t & 63;
        const int f = wv * 16 + (lane & 15);
        const int kbase = (lane >> 4) << 3;
        float part = 0.f;
#pragma unroll
        for (int ks = 0; ks < 2; ++ks)
#pragma unroll
            for (int i = 0; i < 8; ++i) {
                int kin = j * 64 + ks * 32 + kbase + i;
                float v = pw_w[(g * 576 + kin) * 64 + f];
                pwt[((((g * 9 + j) * 4 + wv) * 2 + ks) << 9) + lane * 8 + i] =
                    f2h(v);
                part += v * dw_b[g * 576 + kin];
            }
        atomicAdd(&bias2[g * 64 + f], part);
        // pack dw_w -> dwp f16x2 pairs: dwp[((g*9+tap2)*9 + j)*32 + c/2]
        for (int e = t; e < 288; e += 256) {
            int tap2 = e >> 5, cp = e & 31;
            const float* dwr = &dw_w[(g * 9 + tap2) * 576 + (j << 6) + cp * 2];
            dwp[(((g * 9 + tap2) * 9 + j) << 5) + cp] = pk2h(dwr[0], dwr[1]);
        }
    } else {
        const int s = blockIdx.x - 9;
        const int tap = s >> 1;
        for (int e = t; e < 1024; e += 256) {
            int nt = e >> 9, le = e & 511;
            int lane = le >> 3, i = le & 7;
            int k = ((lane >> 4) << 3) + i;
            int c = ((s & 1) << 5) + k;
            int n = (nt << 4) + (lane & 15);
            float v = (n < 18) ? off_w[((g * 9 + tap) * 64 + c) * 18 + n] : 0.f;
            unsigned short hi = f2bf(v);
            unsigned short lo = f2bf(v - blo(hi));
            int idx = (((g * 18 + s) * 2 + nt) << 9) + le;
            obt[idx] = hi;
            obt[OBT_STRIDE + idx] = lo;
        }
    }
}

// ---------------------------------------------------------------------------
// deform_fused (R4 = R2 structure, f16 stage-1 datapath):
//   Stage 0: offset conv (3x3 SAME, 64->18, split-precision bf16 MFMA) for
//            the 10x10 halo positions, from a 12x12 x-halo -> offs[] in LDS.
//   Stage 1: per tap j: W (bilinear wts) -> S (float4 gather, pkrtz f16) ->
//            A (depthwise via packed f16 FMA, dwp weights) ->
//            B (pointwise mfma_f32_16x16x32_f16).
// LDS union (34,016 B -> 4 blocks/CU):
//   [0,23616):  xh ushort[144*72] (20.7 KB)  ALIASED WITH
//               samp ushort[100*72] @0 + dwa ushort[64*72] @14400
//   [23616..):  offs float[100*18]  (7.2 KB)
//   [30816..):  wlw float4[100] ; wli int4[100]  (3.2 KB)
// ---------------------------------------------------------------------------
__global__ __launch_bounds__(256, 4) void deform_fused(
    const float* __restrict__ x, const unsigned short* __restrict__ obt,
    const float* __restrict__ off_b, const unsigned* __restrict__ dwp,
    const unsigned short* __restrict__ pwt, const float* __restrict__ bias2,
    const float* __restrict__ pw_b, float* __restrict__ out) {
    __shared__ char smem[34016];
    unsigned short* xh = (unsigned short*)smem;            // stage 0 only
    unsigned short* samp = (unsigned short*)smem;          // stage 1 (f16)
    unsigned short* dwa = (unsigned short*)(smem + 14400); // stage 1 (f16)
    float* offs = (float*)(smem + 23616);
    float4* wlw = (float4*)(smem + 30816);
    int4* wli = (int4*)(smem + 32416);

    const int b = blockIdx.x >> 1, g = blockIdx.x & 1;
    const int tileIdx = blockIdx.y;
    const int h0 = (tileIdx >> 4) << 3, w0 = (tileIdx & 15) << 3;
    const int t = threadIdx.x;
    const int lane = t & 63;
    const int wv = __builtin_amdgcn_readfirstlane(t >> 6);
    const int kq = (lane >> 4) << 3;
    const int col = lane & 15;
    const int rq = (lane >> 4) << 2;

    // ================= Stage 0: offset conv for the halo =================
    f32x4 oacc[2][2];
#pragma unroll
    for (int sl = 0; sl < 2; ++sl)
#pragma unroll
        for (int nt = 0; nt < 2; ++nt) oacc[sl][nt] = (f32x4){0.f, 0.f, 0.f, 0.f};
    int mbase[2];
#pragma unroll
    for (int sl = 0; sl < 2; ++sl) {
        int mt = wv + (sl << 2);
        int m = mt * 16 + col;
        if (mt < 7 && m < 100) {
            int opy = m / 10, opx = m - opy * 10;
            mbase[sl] = opy * 12 + opx;
        } else
            mbase[sl] = 0;
    }
    for (int q = 0; q < 2; ++q) {
        if (q) __syncthreads();
        // stage 12x12 halo x 32ch (this q-half), fp32 -> hi/lo bf16
        for (int idx = t; idx < 144 * 8; idx += 256) {
            int sp = idx >> 3, cq = idx & 7;
            int sy = sp / 12, sx = sp - sy * 12;
            int gy = h0 - 2 + sy, gx = w0 - 2 + sx;
            uint2 hp = {0, 0}, lp = {0, 0};
            if ((unsigned)gy < HW && (unsigned)gx < HW) {
                const float4 v = *(const float4*)&x[(((b * HW + gy) * HW + gx)
                                                    << 7) +
                                                   (g << 6) + (q << 5) + (cq << 2)];
                hp.x = pk2bf(v.x, v.y);
                hp.y = pk2bf(v.z, v.w);
                lp.x = pk2bf(v.x - blo(hp.x), v.y - bhi(hp.x));
                lp.y = pk2bf(v.z - blo(hp.y), v.w - bhi(hp.y));
            }
            *(uint2*)&xh[sp * 72 + (cq << 2)] = hp;
            *(uint2*)&xh[sp * 72 + 32 + (cq << 2)] = lp;
        }
        __syncthreads();
        for (int tap = 0; tap < 9; ++tap) {
            const int s = (tap << 1) + q;
            const int ky = tap / 3, kx = tap - ky * 3;
            const int shift = ky * 12 + kx;
            const int bidx = ((g * 18 + s) << 1) << 9;
            s16x8 bh0 = *(const s16x8*)&obt[bidx + lane * 8];
            s16x8 bh1 = *(const s16x8*)&obt[bidx + 512 + lane * 8];
            s16x8 bl0 = *(const s16x8*)&obt[OBT_STRIDE + bidx + lane * 8];
            s16x8 bl1 = *(const s16x8*)&obt[OBT_STRIDE + bidx + 512 + lane * 8];
#pragma unroll
            for (int sl = 0; sl < 2; ++sl) {
                if (wv + (sl << 2) < 7) {   // wave-uniform guard
                    const int base2 = (mbase[sl] + shift) * 72 + kq;
                    s16x8 ah = *(const s16x8*)&xh[base2];
                    s16x8 al = *(const s16x8*)&xh[base2 + 32];
                    oacc[sl][0] = __builtin_amdgcn_mfma_f32_16x16x32_bf16(
                        ah, bh0, oacc[sl][0], 0, 0, 0);
                    oacc[sl][1] = __builtin_amdgcn_mfma_f32_16x16x32_bf16(
                        ah, bh1, oacc[sl][1], 0, 0, 0);
                    oacc[sl][0] = __builtin_amdgcn_mfma_f32_16x16x32_bf16(
                        al, bh0, oacc[sl][0], 0, 0, 0);
                    oacc[sl][1] = __builtin_amdgcn_mfma_f32_16x16x32_bf16(
                        al, bh1, oacc[sl][1], 0, 0, 0);
                    oacc[sl][0] = __builtin_amdgcn_mfma_f32_16x16x32_bf16(
                        ah, bl0, oacc[sl][0], 0, 0, 0);
                    oacc[sl][1] = __builtin_amdgcn_mfma_f32_16x16x32_bf16(
                        ah, bl1, oacc[sl][1], 0, 0, 0);
                }
            }
        }
    }
    // write offs[m][o] = conv + off_b   (C-layout: row = rq+i, col)
#pragma unroll
    for (int sl = 0; sl < 2; ++sl) {
        int mt = wv + (sl << 2);
        if (mt < 7) {
#pragma unroll
            for (int nt = 0; nt < 2; ++nt) {
                int o = (nt << 4) + col;
                if (o < 18) {
                    float ob = off_b[g * 18 + o];
#pragma unroll
                    for (int i = 0; i < 4; ++i) {
                        int m = mt * 16 + rq + i;
                        if (m < 100) offs[m * 18 + o] = oacc[sl][nt][i] + ob;
                    }
                }
            }
        }
    }
    __syncthreads();   // offs visible; xh reads done before samp overwrites

    // ================= Stage 1: sample -> depthwise -> pointwise =========
    const int fb = wv << 4;
    const int p = lane;
    const int ayp = p >> 3, axp = p & 7;
    const int grp = t >> 4, sl16 = t & 15;
    const int pbase = (ayp * 10 + axp) * 72;

    const float bs = bias2[g * 64 + fb + col] + pw_b[g * 64 + fb + col];
    f32x4 acc[4];
#pragma unroll
    for (int mt = 0; mt < 4; ++mt) acc[mt] = (f32x4){bs, bs, bs, bs};

    for (int j = 0; j < 9; ++j) {
        const int jy = j / 3, jx = j - jy * 3;
        f16x8 bfr[2];
#pragma unroll
        for (int ks = 0; ks < 2; ++ks)
            bfr[ks] = *(const f16x8*)&pwt[((((g * 9 + j) * 4 + wv) * 2 + ks)
                                           << 9) + lane * 8];
        // ---- Phase W: bilinear weights + corner offsets, one thread per sp
        if (t < 100) {
            const int sp = t;
            const int spy = sp / 10, spx = sp - spy * 10;
            const int gy = h0 - 1 + spy, gx = w0 - 1 + spx;
            float4 w4 = {0.f, 0.f, 0.f, 0.f};
            int4 ii = {b << 21, 0, 0, 0};
            if ((unsigned)gy < HW && (unsigned)gx < HW) {
                const float ox = offs[sp * 18 + 2 * j];
                const float oy = offs[sp * 18 + 2 * j + 1];
                float xf = fminf(fmaxf((float)(gx + jx - 1) + ox, 0.f), 127.f);
                float yf = fminf(fmaxf((float)(gy + jy - 1) + oy, 0.f), 127.f);
                float x0 = floorf(xf), y0 = floorf(yf);
                float x1 = fminf(x0 + 1.f, 127.f);
                float y1 = fminf(y0 + 1.f, 127.f);
                w4.x = (x1 - xf) * (y1 - yf);
                w4.y = (x1 - xf) * (yf - y0);
                w4.z = (xf - x0) * (y1 - yf);
                w4.w = (xf - x0) * (yf - y0);
                const int x0i = (int)x0, y0i = (int)y0;
                ii.x = ((b * HW + y0i) * HW + x0i) << 7;
                ii.y = ((int)x1 - x0i) << 7;
                ii.z = ((int)y1 - y0i) << 14;
            }
            wlw[sp] = w4;
            wli[sp] = ii;
        }
        __syncthreads();
        // ---- Phase S: float4 gather; 16 lanes per sample position; f16 pack
        for (int it = 0; it < 7; ++it) {
            const int sp = (it << 4) + grp;
            if (sp < 100) {
                const float4 w4 = wlw[sp];
                const int4 ii = wli[sp];
                const float* xa = x + ii.x + (g << 6) + (sl16 << 2);
                const float4 va = *(const float4*)xa;
                const float4 vb = *(const float4*)(xa + ii.z);
                const float4 vc = *(const float4*)(xa + ii.y);
                const float4 vd = *(const float4*)(xa + ii.y + ii.z);
                float r0 = w4.x * va.x + w4.y * vb.x + w4.z * vc.x + w4.w * vd.x;
                float r1 = w4.x * va.y + w4.y * vb.y + w4.z * vc.y + w4.w * vd.y;
                float r2 = w4.x * va.z + w4.y * vb.z + w4.z * vc.z + w4.w * vd.z;
                float r3 = w4.x * va.w + w4.y * vb.w + w4.z * vc.w + w4.w * vd.w;
                uint2 pk;
                pk.x = pk2h(r0, r1);
                pk.y = pk2h(r2, r3);
                *(uint2*)&samp[sp * 72 + (sl16 << 2)] = pk;
            }
        }
        __syncthreads();
        // ---- Phase A: depthwise 3x3 via packed f16 FMA, ch [fb, fb+16)
#pragma unroll
        for (int cq = 0; cq < 2; ++cq) {
            const int c8 = fb + (cq << 3);
            f16x2 d0 = {0, 0}, d1 = {0, 0}, d2 = {0, 0}, d3 = {0, 0};
#pragma unroll
            for (int t2 = 0; t2 < 9; ++t2) {
                const int ky = t2 / 3, kx = t2 - ky * 3;
                const uint4 hv =
                    *(const uint4*)&samp[pbase + (ky * 10 + kx) * 72 + c8];
                const uint4 wq =
                    *(const uint4*)&dwp[(((g * 9 + t2) * 9 + j) << 5) +
                                        (c8 >> 1)];
                d0 = u2h(hv.x) * u2h(wq.x) + d0;   // v_pk_fma_f16
                d1 = u2h(hv.y) * u2h(wq.y) + d1;
                d2 = u2h(hv.z) * u2h(wq.z) + d2;
                d3 = u2h(hv.w) * u2h(wq.w) + d3;
            }
            uint4 pk;
            pk.x = h2u(d0);
            pk.y = h2u(d1);
            pk.z = h2u(d2);
            pk.w = h2u(d3);
            *(uint4*)&dwa[p * 72 + c8] = pk;
        }
        __syncthreads();
        // ---- Phase B: pointwise via f16 MFMA
#pragma unroll
        for (int ks = 0; ks < 2; ++ks)
#pragma unroll
            for (int mt = 0; mt < 4; ++mt) {
                f16x8 af = *(const f16x8*)&dwa[(mt * 16 + col) * 72 + ks * 32 +
                                               kq];
                acc[mt] = __builtin_amdgcn_mfma_f32_16x16x32_f16(
                    af, bfr[ks], acc[mt], 0, 0, 0);
            }
    }
    // ---- epilogue: C-layout col=lane&15, row=(lane>>4)*4+i
#pragma unroll
    for (int mt = 0; mt < 4; ++mt)
#pragma unroll
        for (int i = 0; i < 4; ++i) {
            int m = mt * 16 + rq + i;
            out[((b * HW + h0 + (m >> 3)) * HW + (w0 + (m & 7))) * 128 +
                (g << 6) + fb + col] = acc[mt][i];
        }
}

extern "C" void kernel_launch(void* const* d_in, const int* in_sizes, int n_in,
                              void* d_out, int out_size, void* d_ws,
                              size_t ws_size, hipStream_t stream) {
    const float* x = (const float*)d_in[0];
    const float* off_w = (const float*)d_in[1];
    const float* off_b = (const float*)d_in[2];
    const float* dw_w = (const float*)d_in[3];
    const float* dw_b = (const float*)d_in[4];
    const float* pw_w = (const float*)d_in[5];
    const float* pw_b = (const float*)d_in[6];

    // workspace layout (floats): [pwt | obt | dwp | bias2]
    float* wsf = (float*)d_ws;
    unsigned short* pwt = (unsigned short*)wsf;                // 147456 B
    unsigned short* obt = (unsigned short*)(wsf + PWT_FLOATS); // 147456 B
    unsigned* dwp = (unsigned*)(wsf + PWT_FLOATS + OBT_FLOATS);// 20736 B
    float* bias2 = wsf + PWT_FLOATS + OBT_FLOATS + DWP_WORDS;  // 512 B

    (void)hipMemsetAsync(bias2, 0, GNUM * 64 * sizeof(float), stream);
    prep_kernel<<<dim3(27, GNUM), dim3(256), 0, stream>>>(pw_w, dw_b, off_w,
                                                          dw_w, pwt, obt, dwp,
                                                          bias2);
    deform_fused<<<dim3(BATCH * GNUM, 256), dim3(256), 0, stream>>>(
        x, obt, off_b, dwp, pwt, bias2, pw_b, (float*)d_out);
}